// Round 1
// 802.411 us; speedup vs baseline: 1.2033x; 1.2033x over previous
//
#include <hip/hip_runtime.h>
#include <math.h>

// Problem constants
#define B_ 2
#define S_ 2048
#define H_ 32
#define KV_ 8
#define D_ 128
#define T_ 4096
#define HID_ 4096
#define OQKV_ 6144

typedef __attribute__((ext_vector_type(4))) float f32x4;
typedef __attribute__((ext_vector_type(4))) int i32x4;
typedef __attribute__((ext_vector_type(8))) __bf16 bf16x8;
typedef __attribute__((ext_vector_type(8))) unsigned short u16x8;
typedef unsigned short u16;
typedef signed char s8;

// float -> bf16 bits, RTNE (finite inputs only)
__device__ __forceinline__ u16 f2b(float f) {
  unsigned x = __float_as_uint(f);
  return (u16)((x + 0x7FFFu + ((x >> 16) & 1u)) >> 16);
}
__device__ __forceinline__ float b2f(u16 u) {
  return __uint_as_float(((unsigned)u) << 16);
}

__device__ __forceinline__ void async16(const void* g, void* l) {
  __builtin_amdgcn_global_load_lds((__attribute__((address_space(1))) void*)g,
                                   (__attribute__((address_space(3))) void*)l,
                                   16, 0, 0);
}

__device__ __forceinline__ bf16x8 ld8(const u16* p) { return *(const bf16x8*)p; }

__device__ __forceinline__ f32x4 mfma16x16(bf16x8 a, bf16x8 b, f32x4 c) {
  return __builtin_amdgcn_mfma_f32_16x16x32_bf16(a, b, c, 0, 0, 0);
}

__device__ __forceinline__ bf16x8 ones8() {
  union { u16x8 u; bf16x8 b; } c;
  c.u = u16x8{0x3F80, 0x3F80, 0x3F80, 0x3F80, 0x3F80, 0x3F80, 0x3F80, 0x3F80};
  return c.b;
}

// ---------------- int32 -> int8 pack (values already in int8 range) ----------------
__global__ __launch_bounds__(256) void pack_i8(const int* __restrict__ w,
                                               s8* __restrict__ out) {
  size_t base = ((size_t)blockIdx.x * 256 + threadIdx.x) * 4;
  int4 v = *(const int4*)(w + base);
  unsigned r = (unsigned)(v.x & 255) | ((unsigned)(v.y & 255) << 8) |
               ((unsigned)(v.z & 255) << 16) | ((unsigned)v.w << 24);
  *(unsigned*)(out + base) = r;
}

// NeoX RoPE in-place on bf16 qkv[t][6144]: q heads 0..31, k heads 32..39
__global__ __launch_bounds__(256) void rope_kernel(u16* __restrict__ qkv) {
  int idx = blockIdx.x * 256 + threadIdx.x;   // T * 40 * 64 total
  int t = idx / 2560;
  int r = idx - t * 2560;
  int head = r >> 6;
  int d = r & 63;
  int col = (head < 32) ? (head * 128 + d) : (4096 + (head - 32) * 128 + d);
  size_t base = (size_t)t * 6144 + col;
  float x1 = b2f(qkv[base]);
  float x2 = b2f(qkv[base + 64]);
  float e = (float)d * 0.015625f;                      // d/64 exact
  float freq = exp2f(e * -19.931568569324174f);        // 1e6^-e
  float ang = (float)(t & 2047) * freq;                // pos = t mod S
  float sn, cs;
  sincosf(ang, &sn, &cs);
  qkv[base] = f2b(x1 * cs - x2 * sn);
  qkv[base + 64] = f2b(x2 * cs + x1 * sn);
}

// V slice of qkv -> VT[b][kv][d][s] via LDS tile transpose. grid (32,2,16).
__global__ __launch_bounds__(256) void vt_transpose(const u16* __restrict__ qkv,
                                                    u16* __restrict__ vt) {
  __shared__ u16 tile[64][65];                 // +1 pad kills bank conflicts
  const int s0 = blockIdx.x * 64, d0 = blockIdx.y * 64;
  const int bk = blockIdx.z, b = bk >> 3, kv = bk & 7;
  const int tid = threadIdx.x;
  const int rr = tid >> 3, cc = tid & 7;
#pragma unroll
  for (int it = 0; it < 2; it++) {
    int r = it * 32 + rr;
    u16x8 v = *(const u16x8*)(qkv + (size_t)(b * 2048 + s0 + r) * 6144 + 5120 +
                              kv * 128 + d0 + cc * 8);
#pragma unroll
    for (int k = 0; k < 8; k++) tile[r][cc * 8 + k] = v[k];
  }
  __syncthreads();
#pragma unroll
  for (int it = 0; it < 2; it++) {
    int d = it * 32 + rr;
    u16x8 o;
#pragma unroll
    for (int k = 0; k < 8; k++) o[k] = tile[cc * 8 + k][d];
    *(u16x8*)(vt + (size_t)(bk * 128 + d0 + d) * 2048 + s0 + cc * 8) = o;
  }
}

// ---------------- int8 GEMM with per-128-group scales ----------------
// C[m,n] = rowscale[m] * sum_g sB[n,g] * sum_{k in g} A[m,k]*Bw[n,k]
// Tiles 128x128, BK=64 (one mfma_i32_16x16x64_i8 per fragment per step).
// LDS chunk rotation keyed on row>>1 (64B rows alias mod-2 in banks; the
// rotation spreads the 4 16B chunks so quarter-wave reads are ~2-way).
__device__ __forceinline__ void store_out(float* p, float v) { *p = v; }
__device__ __forceinline__ void store_out(u16* p, float v) { *p = f2b(v); }

template <typename OutT>
__global__ __launch_bounds__(256) void gemm_i8(const s8* __restrict__ A,
                                               const s8* __restrict__ Bw,
                                               const float* __restrict__ sB,
                                               const float* __restrict__ rowscale,
                                               OutT* __restrict__ C,
                                               int M, int N, int K) {
  __shared__ __align__(16) s8 As[128 * 64];
  __shared__ __align__(16) s8 Bs[128 * 64];
  __shared__ float Ss[128][33];                // [local n][group], padded
  const int tid = threadIdx.x;
  const int lane = tid & 63;
  const int wv = tid >> 6;
  const int wm = wv >> 1, wn = wv & 1;
  const int m0 = blockIdx.y * 128, n0 = blockIdx.x * 128;
  const int g = lane >> 4, c15 = lane & 15;
  const int KG = K >> 7;                       // 32 groups for K=4096

  // preload this block's scale panel (contiguous, coalesced)
  for (int i = tid; i < 128 * 32; i += 256)
    Ss[i >> 5][i & 31] = sB[(size_t)n0 * 32 + i];

  f32x4 acc[4][4] = {};

  const int c0 = 2 * wv, c1 = c0 + 1;          // this wave's staging chunks
  const int srow = lane >> 2;                  // 0..15 row within chunk
  const int pch = lane & 3;                    // physical 16B chunk slot
  const int scol = (((pch - (srow >> 1)) & 3)) * 16;  // logical chunk -> col
  const s8* Ag0 = A + (size_t)(m0 + c0 * 16 + srow) * K + scol;
  const s8* Ag1 = A + (size_t)(m0 + c1 * 16 + srow) * K + scol;
  const s8* Bg0 = Bw + (size_t)(n0 + c0 * 16 + srow) * K + scol;
  const s8* Bg1 = Bw + (size_t)(n0 + c1 * 16 + srow) * K + scol;
  s8* Al0 = As + c0 * 1024 + lane * 16;
  s8* Al1 = As + c1 * 1024 + lane * 16;
  s8* Bl0 = Bs + c0 * 1024 + lane * 16;
  s8* Bl1 = Bs + c1 * 1024 + lane * 16;

  for (int grp = 0; grp < KG; grp++) {
    i32x4 iacc[4][4];
#pragma unroll
    for (int sub = 0; sub < 2; sub++) {
      const int kb = grp * 128 + sub * 64;
      __syncthreads();
      async16(Ag0 + kb, Al0);
      async16(Ag1 + kb, Al1);
      async16(Bg0 + kb, Bl0);
      async16(Bg1 + kb, Bl1);
      __syncthreads();
      i32x4 af[4], bf[4];
#pragma unroll
      for (int i = 0; i < 4; i++) {
        af[i] = *(const i32x4*)(As + (wm * 64 + i * 16 + c15) * 64 +
                                ((g + (c15 >> 1)) & 3) * 16);
        bf[i] = *(const i32x4*)(Bs + (wn * 64 + i * 16 + c15) * 64 +
                                ((g + (c15 >> 1)) & 3) * 16);
      }
#pragma unroll
      for (int i = 0; i < 4; i++)
#pragma unroll
        for (int j = 0; j < 4; j++)
          iacc[i][j] = __builtin_amdgcn_mfma_i32_16x16x64_i8(
              af[i], bf[j], sub ? iacc[i][j] : (i32x4){0, 0, 0, 0}, 0, 0, 0);
    }
    // per-group rescale into fp32 master accumulator
#pragma unroll
    for (int j = 0; j < 4; j++) {
      const float sc = Ss[wn * 64 + j * 16 + c15][grp];
#pragma unroll
      for (int i = 0; i < 4; i++)
#pragma unroll
        for (int r = 0; r < 4; r++)
          acc[i][j][r] += sc * (float)iacc[i][j][r];
    }
  }

#pragma unroll
  for (int i = 0; i < 4; i++) {
#pragma unroll
    for (int r = 0; r < 4; r++) {
      int m = m0 + wm * 64 + i * 16 + g * 4 + r;
      float scm = rowscale[m];
#pragma unroll
      for (int j = 0; j < 4; j++) {
        int n = n0 + wn * 64 + j * 16 + c15;
        store_out(C + (size_t)m * N + n, acc[i][j][r] * scm);
      }
    }
  }
}

// ---------------- flash attention (causal, GQA 4:1) ----------------
struct AttnState {
  f32x4 acc[2][9];
  float mrun[2][4];
};

template <bool FULL>
__device__ __forceinline__ void attn_step(
    int j0, int q0, const u16* kbase, const u16* vbase, u16* pw0, u16* pw1,
    const bf16x8 qf[2][4], AttnState& st, int g, int c15, const bf16x8 vones) {
  const int qmax = q0 + 31;
  f32x4 sc[2][4];
#pragma unroll
  for (int nt = 0; nt < 4; nt++) {
    if (FULL || (j0 + nt * 16 <= qmax)) {
      bf16x8 kf[4];
      const u16* kp = kbase + (size_t)(j0 + nt * 16) * 6144;
#pragma unroll
      for (int c = 0; c < 4; c++) kf[c] = ld8(kp + c * 32);
      f32x4 s0 = {0.f, 0.f, 0.f, 0.f}, s1 = {0.f, 0.f, 0.f, 0.f};
#pragma unroll
      for (int c = 0; c < 4; c++) {
        s0 = mfma16x16(qf[0][c], kf[c], s0);
        s1 = mfma16x16(qf[1][c], kf[c], s1);
      }
      if (FULL) {
#pragma unroll
        for (int r = 0; r < 4; r++) {
          sc[0][nt][r] = s0[r] * 0.08838834764831845f;
          sc[1][nt][r] = s1[r] * 0.08838834764831845f;
        }
      } else {
        const int key = j0 + nt * 16 + c15;
#pragma unroll
        for (int r = 0; r < 4; r++) {
          sc[0][nt][r] =
              (key <= q0 + g * 4 + r) ? s0[r] * 0.08838834764831845f : -INFINITY;
          sc[1][nt][r] =
              (key <= q0 + 16 + g * 4 + r) ? s1[r] * 0.08838834764831845f : -INFINITY;
        }
      }
    }
  }
  // online softmax per m-tile
#pragma unroll
  for (int m = 0; m < 2; m++) {
    u16* pw = m ? pw1 : pw0;
    float alpha[4];
#pragma unroll
    for (int r = 0; r < 4; r++) {
      float rm = -INFINITY;
#pragma unroll
      for (int nt = 0; nt < 4; nt++)
        if (FULL || (j0 + nt * 16 <= qmax)) rm = fmaxf(rm, sc[m][nt][r]);
      rm = fmaxf(rm, __shfl_xor(rm, 1));
      rm = fmaxf(rm, __shfl_xor(rm, 2));
      rm = fmaxf(rm, __shfl_xor(rm, 4));
      rm = fmaxf(rm, __shfl_xor(rm, 8));
      float mnew = fmaxf(st.mrun[m][r], rm);
      alpha[r] = __expf(st.mrun[m][r] - mnew);
      st.mrun[m][r] = mnew;
#pragma unroll
      for (int nt = 0; nt < 4; nt++) {
        float pv = (FULL || (j0 + nt * 16 <= qmax))
                       ? __expf(sc[m][nt][r] - mnew) : 0.0f;
        pw[(g * 4 + r) * 72 + nt * 16 + c15] = f2b(pv);
      }
    }
#pragma unroll
    for (int dt = 0; dt < 9; dt++)
#pragma unroll
      for (int r = 0; r < 4; r++) st.acc[m][dt][r] *= alpha[r];
  }
  // PV: V fragments straight from global; ones-column accumulates l
#pragma unroll
  for (int kc = 0; kc < 2; kc++) {
    bf16x8 pf0 = ld8(pw0 + c15 * 72 + kc * 32 + g * 8);
    bf16x8 pf1 = ld8(pw1 + c15 * 72 + kc * 32 + g * 8);
#pragma unroll
    for (int dt = 0; dt < 8; dt++) {
      bf16x8 vf = ld8(vbase + (size_t)(dt * 16) * 2048 + j0 + kc * 32);
      st.acc[0][dt] = mfma16x16(pf0, vf, st.acc[0][dt]);
      st.acc[1][dt] = mfma16x16(pf1, vf, st.acc[1][dt]);
    }
    st.acc[0][8] = mfma16x16(pf0, vones, st.acc[0][8]);
    st.acc[1][8] = mfma16x16(pf1, vones, st.acc[1][8]);
  }
}

// grid (8, 32, 2), block 256. Wave wv handles pair a = blockIdx.x*4+wv.
__global__ __launch_bounds__(256, 2) void attn_kernel(const u16* __restrict__ qkvb,
                                                      const u16* __restrict__ vtb,
                                                      float* __restrict__ out) {
  __shared__ __align__(16) u16 Ps[4][2][16 * 72];   // per-wave, per-m-tile P
  const int tid = threadIdx.x, lane = tid & 63, wv = tid >> 6;
  const int g = lane >> 4, c15 = lane & 15;
  const int a = blockIdx.x * 4 + wv;                // 0..31
  const int h = blockIdx.y, b = blockIdx.z, kvh = h >> 2;
  const bf16x8 vones = ones8();
  const u16* kbase =
      qkvb + (size_t)(b * 2048 + c15) * 6144 + 4096 + kvh * 128 + g * 8;
  const u16* vbase = vtb + (size_t)((b * 8 + kvh) * 128 + c15) * 2048 + g * 8;
  u16* pw0 = &Ps[wv][0][0];
  u16* pw1 = &Ps[wv][1][0];

  for (int half = 0; half < 2; half++) {
    const int qt = half ? (63 - a) : a;
    const int q0 = qt * 32;
    bf16x8 qf[2][4];
#pragma unroll
    for (int m = 0; m < 2; m++) {
      const u16* qp =
          qkvb + (size_t)(b * 2048 + q0 + m * 16 + c15) * 6144 + h * 128 + g * 8;
#pragma unroll
      for (int c = 0; c < 4; c++) qf[m][c] = ld8(qp + c * 32);
    }
    AttnState st;
#pragma unroll
    for (int m = 0; m < 2; m++)
#pragma unroll
      for (int dt = 0; dt < 9; dt++) st.acc[m][dt] = f32x4{0.f, 0.f, 0.f, 0.f};
#pragma unroll
    for (int m = 0; m < 2; m++)
#pragma unroll
      for (int r = 0; r < 4; r++) st.mrun[m][r] = -INFINITY;

    const int nfull = qt >> 1;                 // full 64-key steps
    for (int jt = 0; jt < nfull; jt++)
      attn_step<true>(jt * 64, q0, kbase, vbase, pw0, pw1, qf, st, g, c15, vones);
    attn_step<false>(nfull * 64, q0, kbase, vbase, pw0, pw1, qf, st, g, c15, vones);

    // epilogue: normalize by l (= acc[8]) and store fp32
#pragma unroll
    for (int m = 0; m < 2; m++)
#pragma unroll
      for (int r = 0; r < 4; r++) {
        const int row = q0 + m * 16 + g * 4 + r;
        float inv = 1.0f / st.acc[m][8][r];
        float* op = out + (size_t)(b * 2048 + row) * 4096 + h * 128;
#pragma unroll
        for (int dt = 0; dt < 8; dt++) op[dt * 16 + c15] = st.acc[m][dt][r] * inv;
      }
  }
}

// ---------------- per-row quantization (fp32 attn -> int8 + scale) ----------------
__global__ __launch_bounds__(256) void quant_kernel(const float* __restrict__ attn,
                                                    s8* __restrict__ aq,
                                                    float* __restrict__ ascale) {
  const int t = blockIdx.x, tid = threadIdx.x;
  const float* row = attn + (size_t)t * 4096;
  f32x4 v[4];
  float am = 0.f;
#pragma unroll
  for (int i = 0; i < 4; i++) {
    v[i] = *(const f32x4*)(row + tid * 16 + i * 4);
#pragma unroll
    for (int r = 0; r < 4; r++) am = fmaxf(am, fabsf(v[i][r]));
  }
#pragma unroll
  for (int m = 1; m <= 32; m <<= 1) am = fmaxf(am, __shfl_xor(am, m));
  __shared__ float red[4];
  if ((tid & 63) == 0) red[tid >> 6] = am;
  __syncthreads();
  am = fmaxf(fmaxf(red[0], red[1]), fmaxf(red[2], red[3]));
  float asc = fmaxf(am, 1e-6f) / 127.0f;
  if (tid == 0) ascale[t] = asc;
  int w[4];
#pragma unroll
  for (int i = 0; i < 4; i++) {
    int bytes[4];
#pragma unroll
    for (int r = 0; r < 4; r++) {
      float q = rintf(v[i][r] / asc);
      q = fminf(127.0f, fmaxf(-127.0f, q));
      bytes[r] = ((int)q) & 255;
    }
    w[i] = bytes[0] | (bytes[1] << 8) | (bytes[2] << 16) | (bytes[3] << 24);
  }
  *(int4*)(aq + (size_t)t * 4096 + tid * 16) = int4{w[0], w[1], w[2], w[3]};
}

// ---------------- launch ----------------
extern "C" void kernel_launch(void* const* d_in, const int* in_sizes, int n_in,
                              void* d_out, int out_size, void* d_ws, size_t ws_size,
                              hipStream_t stream) {
  const int* q_hidden = (const int*)d_in[0];
  const float* q_scale = (const float*)d_in[1];
  const int* w_qkv = (const int*)d_in[3];
  const float* s_qkv = (const float*)d_in[4];
  const int* w_o = (const int*)d_in[5];
  const float* s_o = (const float*)d_in[6];
  float* out = (float*)d_out;

  char* ws = (char*)d_ws;
  const size_t MB = 1024 * 1024;
  // ws layout (96 MB peak, regions reused across phases):
  s8* WB = (s8*)(ws);                  // [0,24MB) w_qkv i8 (dead after gemm1)
  u16* QKVB = (u16*)(ws + 48 * MB);    // [48,96MB) qkv bf16 (dead after attention)
  u16* VTB = (u16*)(ws);               // [0,8MB) V^T (after gemm1)
  s8* ATTNQ = (s8*)(ws + 8 * MB);      // [8,~24.8MB) attn_q i8
  float* ASC = (float*)(ws + 25 * MB); // [25MB,+16KB) per-row scales
  s8* WOB = (s8*)(ws + 48 * MB);       // [48,~64.8MB) w_o i8 (after attention)
  s8* XB = (s8*)d_out;                 // x i8 in d_out (dead after gemm1)

  pack_i8<<<16384, 256, 0, stream>>>(q_hidden, XB);
  pack_i8<<<24576, 256, 0, stream>>>(w_qkv, WB);
  gemm_i8<u16><<<dim3(48, 32), 256, 0, stream>>>(XB, WB, s_qkv, q_scale, QKVB,
                                                 T_, OQKV_, HID_);
  rope_kernel<<<40960, 256, 0, stream>>>(QKVB);
  vt_transpose<<<dim3(32, 2, 16), 256, 0, stream>>>(QKVB, VTB);
  attn_kernel<<<dim3(8, 32, 2), 256, 0, stream>>>(QKVB, VTB, out);
  quant_kernel<<<4096, 256, 0, stream>>>(out, ATTNQ, ASC);
  pack_i8<<<16384, 256, 0, stream>>>(w_o, WOB);
  gemm_i8<float><<<dim3(32, 32), 256, 0, stream>>>(ATTNQ, WOB, s_o, ASC, out,
                                                   T_, HID_, HID_);
}